// Round 3
// baseline (580.825 us; speedup 1.0000x reference)
//
#include <hip/hip_runtime.h>

#define POOL 14
#define NUM_ROIS 512
#define NUM_ITEMS (NUM_ROIS * POOL)   // 7168
#define IMG_H 200
#define IMG_W 200
#define IMG_C 1024
#define NUM_XCD 8
#define XBINS 8
#define NBINS (IMG_H * XBINS)         // 1600 bins: (image_row, x/32)
#define CHUNK 112                     // items/chunk; 64 chunks; 8 per XCD
#define SORT_THREADS 1024
#define BINS_PER_THREAD 2             // 1024*2 = 2048 >= 1600

typedef float v4f __attribute__((ext_vector_type(4)));

// Sort key: the image row this (roi,py) item reads (its y0 row), plus
// coarse x. Items with equal/adjacent keys read overlapping image bytes.
__device__ __forceinline__ int item_key(const int* __restrict__ rois,
                                        int i, int* out_code) {
    const int r  = i / POOL;
    const int py = i - r * POOL;
    const int4 box = ((const int4*)rois)[r];  // x,y,w,h
    const float stepy = (float)box.w / (float)POOL;   // box.w == h
    const float sy = (float)py * stepy;
    const int y0  = (int)floorf(sy);
    const int y0c = min(max(y0, 0), box.w - 1);
    const int row = box.y + y0c;              // 0..199
    *out_code = (r << 4) | py;
    return row * XBINS + (box.x >> 5);
}

// Global counting sort of all 7168 items by (image_row, x/32).
// Single block, 1024 threads. perm[pos] = (r<<4)|py.
__global__ __launch_bounds__(SORT_THREADS) void order_kernel(
    const int* __restrict__ rois, int* __restrict__ perm) {
    const int tid = threadIdx.x;
    __shared__ int hist[NBINS];
    __shared__ int cnt[NBINS];
    __shared__ int partial[SORT_THREADS];

    for (int k = tid; k < NBINS; k += SORT_THREADS) { hist[k] = 0; cnt[k] = 0; }
    __syncthreads();

    for (int i = tid; i < NUM_ITEMS; i += SORT_THREADS) {
        int code;
        atomicAdd(&hist[item_key(rois, i, &code)], 1);
    }
    __syncthreads();

    // Exclusive scan over hist[NBINS]: per-thread sums + Hillis-Steele.
    const int b0 = tid * BINS_PER_THREAD;
    int lsum[BINS_PER_THREAD];
    int local = 0;
    for (int j = 0; j < BINS_PER_THREAD; ++j) {
        const int k = b0 + j;
        lsum[j] = local;
        if (k < NBINS) local += hist[k];
    }
    partial[tid] = local;
    __syncthreads();
    for (int off = 1; off < SORT_THREADS; off <<= 1) {
        const int add = (tid >= off) ? partial[tid - off] : 0;
        __syncthreads();
        partial[tid] += add;
        __syncthreads();
    }
    const int chunk_excl = partial[tid] - local;
    for (int j = 0; j < BINS_PER_THREAD; ++j) {
        const int k = b0 + j;
        if (k < NBINS) hist[k] = chunk_excl + lsum[j];
    }
    __syncthreads();

    for (int i = tid; i < NUM_ITEMS; i += SORT_THREADS) {
        int code;
        const int key = item_key(rois, i, &code);
        const int pos = hist[key] + atomicAdd(&cnt[key], 1);
        perm[pos] = code;
    }
}

// One block (256 threads) per (roi, py) item: 14 cells, each thread owns 4
// channels. The row-sorted item list is cut into 64 chunks of 112 (~3 image
// rows each); chunk c goes to XCD c%8 (hardware round-robins blockIdx%8).
// Each XCD sweeps 8 disjoint row-contiguous slices of the image, so a given
// image row is fetched into ~1 L2 instead of all 8: cross-XCD read
// duplication collapses toward the unique-footprint floor.
__global__ __launch_bounds__(256) void roi_row_kernel(
    const float* __restrict__ img,   // (200,200,1024)
    const int*   __restrict__ rois,  // (512,4) x,y,w,h
    const int*   __restrict__ perm,  // row-sorted work list, or null
    float*       __restrict__ out)   // (512,14,14,1024)
{
    const int b = blockIdx.x;        // 0 .. 7167
    int r, py;
    if (perm) {
        const int xcd = b & (NUM_XCD - 1);
        const int t   = b >> 3;          // 0..895 (per-XCD sequence)
        const int cl  = t / CHUNK;       // which of my 8 chunks (0..7)
        const int j   = t - cl * CHUNK;
        const int pos = (xcd + NUM_XCD * cl) * CHUNK + j;
        const int code = perm[pos];
        r  = code >> 4;
        py = code & 15;
    } else {
        r  = b / POOL;
        py = b - r * POOL;
    }

    const int4 box = ((const int4*)rois)[r];
    const int bx = box.x, by = box.y, bw = box.z, bh = box.w;

    // jnp f32 semantics: s = arange(POOL) * (dim / 14.0f)
    const float stepy = (float)bh / (float)POOL;
    const float stepx = (float)bw / (float)POOL;

    const float sy = (float)py * stepy;
    const int   y0 = (int)floorf(sy);
    const float wy = sy - (float)y0;
    const int y0c = min(max(y0, 0), bh - 1);
    const int y1c = min(max(y0 + 1, 0), bh - 1);

    const float* __restrict__ row0 = img + (size_t)(by + y0c) * IMG_W * IMG_C;
    const float* __restrict__ row1 = img + (size_t)(by + y1c) * IMG_W * IMG_C;

    const int c = threadIdx.x * 4;
    float* __restrict__ orow =
        out + ((size_t)r * (POOL * POOL) + (size_t)py * POOL) * IMG_C + c;

#pragma unroll
    for (int px = 0; px < POOL; ++px) {
        const float sx = (float)px * stepx;
        const int   x0 = (int)floorf(sx);
        const float wx = sx - (float)x0;
        const int x0c = min(max(x0, 0), bw - 1);
        const int x1c = min(max(x0 + 1, 0), bw - 1);
        const int ix0 = bx + x0c;
        const int ix1 = bx + x1c;

        const v4f g00 = *(const v4f*)(row0 + (size_t)ix0 * IMG_C + c);
        const v4f g01 = *(const v4f*)(row0 + (size_t)ix1 * IMG_C + c);
        const v4f g10 = *(const v4f*)(row1 + (size_t)ix0 * IMG_C + c);
        const v4f g11 = *(const v4f*)(row1 + (size_t)ix1 * IMG_C + c);

        const v4f top = g00 + (g01 - g00) * wx;
        const v4f bot = g10 + (g11 - g10) * wx;
        const v4f res = top + (bot - top) * wy;

        // Write-once stream: non-temporal keeps it out of L1/L2.
        __builtin_nontemporal_store(res, (v4f*)(orow + (size_t)px * IMG_C));
    }
}

extern "C" void kernel_launch(void* const* d_in, const int* in_sizes, int n_in,
                              void* d_out, int out_size, void* d_ws, size_t ws_size,
                              hipStream_t stream) {
    const float* img  = (const float*)d_in[0];
    const int*   rois = (const int*)d_in[1];
    float*       out  = (float*)d_out;

    int* perm = nullptr;
    if (d_ws && ws_size >= (size_t)NUM_ITEMS * sizeof(int)) {
        perm = (int*)d_ws;
        order_kernel<<<1, SORT_THREADS, 0, stream>>>(rois, perm);
    }
    roi_row_kernel<<<NUM_ITEMS, 256, 0, stream>>>(img, rois, perm, out);
}

// Round 4
// 574.164 us; speedup vs baseline: 1.0116x; 1.0116x over previous
//
#include <hip/hip_runtime.h>

#define POOL 14
#define NUM_ROIS 512
#define NUM_ITEMS (NUM_ROIS * POOL)          // 7168
#define IMG_H 200
#define IMG_W 200
#define IMG_C 1024
#define NUM_XCD 8
#define ROIS_PER_XCD (NUM_ROIS / NUM_XCD)    // 64
#define ITEMS_PER_XCD (ROIS_PER_XCD * POOL)  // 896
#define XBINS 8
#define NBINS (IMG_H * XBINS)                // 1600
#define BINS_PER_THREAD 7                    // 256*7 = 1792 >= 1600

typedef float v4f __attribute__((ext_vector_type(4)));

// Sort key for a (roi, py) work item: the image row it reads + coarse x.
// Items with equal/adjacent keys read overlapping image bytes, so running
// them concurrently on one XCD turns shared segments into L2 hits.
__device__ __forceinline__ int item_key(const int* __restrict__ rois,
                                        int xcd, int i, int* out_code) {
    const int roi_in = i / POOL;
    const int py     = i - roi_in * POOL;
    const int r      = xcd * ROIS_PER_XCD + roi_in;
    const int4 box   = ((const int4*)rois)[r];  // x,y,w,h
    const float stepy = (float)box.w / (float)POOL;
    const float sy    = (float)py * stepy;
    const int y0  = (int)floorf(sy);
    const int y0c = min(max(y0, 0), box.w - 1);
    const int row = box.y + y0c;                 // 0..199
    *out_code = (r << 4) | py;
    return row * XBINS + (box.x >> 5);           // (row, x/32)
}

// Counting sort of each XCD's 896 items by (image_row, x/32).
// One block per XCD (parallel, ~8 us); perm[xcd*896 + s] = (r<<4)|py.
__global__ __launch_bounds__(256) void order_kernel(
    const int* __restrict__ rois, int* __restrict__ perm) {
    const int xcd = blockIdx.x;
    const int tid = threadIdx.x;
    __shared__ int hist[NBINS];
    __shared__ int cnt[NBINS];
    __shared__ int partial[256];

    for (int k = tid; k < NBINS; k += 256) { hist[k] = 0; cnt[k] = 0; }
    __syncthreads();

    for (int i = tid; i < ITEMS_PER_XCD; i += 256) {
        int code;
        atomicAdd(&hist[item_key(rois, xcd, i, &code)], 1);
    }
    __syncthreads();

    // Exclusive scan of hist[NBINS]: per-thread chunk sums + Hillis-Steele.
    const int b0 = tid * BINS_PER_THREAD;
    int lsum[BINS_PER_THREAD];
    int local = 0;
    for (int j = 0; j < BINS_PER_THREAD; ++j) {
        const int k = b0 + j;
        lsum[j] = local;
        if (k < NBINS) local += hist[k];
    }
    partial[tid] = local;
    __syncthreads();
    for (int off = 1; off < 256; off <<= 1) {
        const int add = (tid >= off) ? partial[tid - off] : 0;
        __syncthreads();
        partial[tid] += add;
        __syncthreads();
    }
    const int chunk_excl = partial[tid] - local;
    for (int j = 0; j < BINS_PER_THREAD; ++j) {
        const int k = b0 + j;
        if (k < NBINS) hist[k] = chunk_excl + lsum[j];
    }
    __syncthreads();

    for (int i = tid; i < ITEMS_PER_XCD; i += 256) {
        int code;
        const int key = item_key(rois, xcd, i, &code);
        const int pos = hist[key] + atomicAdd(&cnt[key], 1);
        perm[xcd * ITEMS_PER_XCD + pos] = code;
    }
}

// One block (256 threads) per (roi, py) row: each thread owns 4 channels.
// ROI -> XCD confinement (blockIdx&7) + row-sorted per-XCD order (perm).
//
// Inner loop processes px in PAIRS: 8 independent dwordx4 loads are issued
// per body before any use, doubling per-wave memory-level parallelism.
// All 14 corner addresses are precomputed up front (statically indexed
// after unroll -> registers) so the loop is pure loads + lerp + nt stores.
__global__ __launch_bounds__(256) void roi_row_kernel(
    const float* __restrict__ img,   // (200,200,1024)
    const int*   __restrict__ rois,  // (512,4) x,y,w,h
    const int*   __restrict__ perm,  // sorted work list, or null
    float*       __restrict__ out)   // (512,14,14,1024)
{
    const int b = blockIdx.x;        // 0 .. 7167
    int r, py;
    if (perm) {
        const int code = perm[(b & (NUM_XCD - 1)) * ITEMS_PER_XCD + (b >> 3)];
        r  = code >> 4;
        py = code & 15;
    } else {
        const int xcd = b & (NUM_XCD - 1);
        const int s   = b >> 3;
        const int roi_in = s / POOL;
        py = s - roi_in * POOL;
        r  = xcd * ROIS_PER_XCD + roi_in;
    }

    const int4 box = ((const int4*)rois)[r];
    const int bx = box.x, by = box.y, bw = box.z, bh = box.w;

    // jnp f32 semantics: s = arange(POOL) * (dim / 14.0f)
    const float stepy = (float)bh / (float)POOL;
    const float stepx = (float)bw / (float)POOL;

    const float sy = (float)py * stepy;
    const int   y0 = (int)floorf(sy);
    const float wy = sy - (float)y0;
    const int y0c = min(max(y0, 0), bh - 1);
    const int y1c = min(max(y0 + 1, 0), bh - 1);

    const int c = threadIdx.x * 4;
    const float* __restrict__ r0c =
        img + (size_t)(by + y0c) * IMG_W * IMG_C + c;
    const float* __restrict__ r1c =
        img + (size_t)(by + y1c) * IMG_W * IMG_C + c;
    float* __restrict__ orow =
        out + ((size_t)r * (POOL * POOL) + (size_t)py * POOL) * IMG_C + c;

    // Precompute all corner columns + weights (registers after unroll).
    int ixa[POOL][2];
    float wxa[POOL];
#pragma unroll
    for (int px = 0; px < POOL; ++px) {
        const float sx = (float)px * stepx;
        const int   x0 = (int)floorf(sx);
        wxa[px]    = sx - (float)x0;
        ixa[px][0] = bx + min(max(x0, 0), bw - 1);
        ixa[px][1] = bx + min(max(x0 + 1, 0), bw - 1);
    }

#pragma unroll
    for (int it = 0; it < POOL / 2; ++it) {
        const int pa = 2 * it, pb = 2 * it + 1;

        const v4f a00 = *(const v4f*)(r0c + (size_t)ixa[pa][0] * IMG_C);
        const v4f a01 = *(const v4f*)(r0c + (size_t)ixa[pa][1] * IMG_C);
        const v4f a10 = *(const v4f*)(r1c + (size_t)ixa[pa][0] * IMG_C);
        const v4f a11 = *(const v4f*)(r1c + (size_t)ixa[pa][1] * IMG_C);
        const v4f b00 = *(const v4f*)(r0c + (size_t)ixa[pb][0] * IMG_C);
        const v4f b01 = *(const v4f*)(r0c + (size_t)ixa[pb][1] * IMG_C);
        const v4f b10 = *(const v4f*)(r1c + (size_t)ixa[pb][0] * IMG_C);
        const v4f b11 = *(const v4f*)(r1c + (size_t)ixa[pb][1] * IMG_C);

        const float wxA = wxa[pa];
        const float wxB = wxa[pb];

        const v4f topA = a00 + (a01 - a00) * wxA;
        const v4f botA = a10 + (a11 - a10) * wxA;
        const v4f resA = topA + (botA - topA) * wy;
        const v4f topB = b00 + (b01 - b00) * wxB;
        const v4f botB = b10 + (b11 - b10) * wxB;
        const v4f resB = topB + (botB - topB) * wy;

        // Write-once stream: non-temporal keeps it out of L1/L2.
        __builtin_nontemporal_store(resA, (v4f*)(orow + (size_t)pa * IMG_C));
        __builtin_nontemporal_store(resB, (v4f*)(orow + (size_t)pb * IMG_C));
    }
}

extern "C" void kernel_launch(void* const* d_in, const int* in_sizes, int n_in,
                              void* d_out, int out_size, void* d_ws, size_t ws_size,
                              hipStream_t stream) {
    const float* img  = (const float*)d_in[0];
    const int*   rois = (const int*)d_in[1];
    float*       out  = (float*)d_out;

    int* perm = nullptr;
    if (d_ws && ws_size >= (size_t)NUM_ITEMS * sizeof(int)) {
        perm = (int*)d_ws;
        order_kernel<<<NUM_XCD, 256, 0, stream>>>(rois, perm);
    }
    roi_row_kernel<<<NUM_ITEMS, 256, 0, stream>>>(img, rois, perm, out);
}